// Round 1
// baseline (4390.985 us; speedup 1.0000x reference)
//
#include <hip/hip_runtime.h>

#define BB 512
#define TT 256
#define SS 32
#define MM 4
#define LDP 33   // padded stride for 32-wide rows: bank = (row+col)%32, conflict-free
#define LDV 5    // padded stride for 32x4 arrays

__global__ __launch_bounds__(256, 2)
void kalman_fp32(const float* __restrict__ obs,       // [B,T,M]
                 const float* __restrict__ Fg,        // [S,S]
                 const float* __restrict__ Qg,        // [S,S]
                 const float* __restrict__ Hg,        // [M,S]
                 const float* __restrict__ Rg,        // [M,M]
                 const float* __restrict__ init_mean, // [B,S]
                 const float* __restrict__ init_cov,  // [B,S,S]
                 float* __restrict__ out)             // means [T,B,M] ++ covs [T,B,M,M]
{
    // sP has 33 rows: row 32 holds the state mean m (so PHt phase computes mm for free)
    __shared__ float sP[(SS + 1) * LDP];
    __shared__ float sFP[SS * LDP];      // FP = F*P, then temp = F*P_u in place
    __shared__ float sQ[SS * LDP];
    __shared__ float sF[SS * LDP];
    __shared__ float sR[MM * MM];
    __shared__ float sPHt[(SS + 1) * LDV]; // row 32 unused
    __shared__ float sFPH[SS * LDV];
    __shared__ float sFK[SS * LDV];
    __shared__ float sSm[MM * MM];
    __shared__ float smm[MM];
    __shared__ float sFm[SS];
    __shared__ float sresid[MM];

    const int tid = threadIdx.x;
    const int b   = blockIdx.x;
    const int a   = tid >> 5;   // 0..7 : this thread owns F rows 4a..4a+3
    const int j   = tid & 31;   // column index for big matmuls

    float* sm = &sP[SS * LDP];  // mean lives as row 32 of sP

    // ---- register-resident F rows (reused in phase 1 and phase 5) ----
    float Freg[4][SS];
    #pragma unroll
    for (int r = 0; r < 4; ++r)
        #pragma unroll
        for (int k = 0; k < SS; ++k)
            Freg[r][k] = Fg[(4 * a + r) * SS + k];

    // ---- register-resident H row (tid&3) ----
    float Hreg[SS];
    #pragma unroll
    for (int k = 0; k < SS; ++k)
        Hreg[k] = Hg[(tid & 3) * SS + k];

    // ---- stage LDS ----
    for (int e = tid; e < SS * SS; e += 256) {
        int r = e >> 5, c = e & 31;
        sP[r * LDP + c] = init_cov[(size_t)b * SS * SS + e];
        sQ[r * LDP + c] = Qg[e];
        sF[r * LDP + c] = Fg[e];
    }
    if (tid < SS) sm[tid] = init_mean[b * SS + tid];
    if (tid < MM * MM) sR[tid] = Rg[tid];
    __syncthreads();

    float* out_means = out;
    float* out_covs  = out + (size_t)TT * BB * MM;

    for (int t = 0; t < TT; ++t) {
        // ================= phase 1 =================
        // prefetch observation early (consumed in phase 2)
        float yv = 0.f;
        if (tid >= 144 && tid < 148)
            yv = obs[((size_t)b * TT + t) * MM + (tid - 144)];

        // FP[4a+r][j] = sum_k F[4a+r][k] * P[k][j]
        {
            float acc0 = 0.f, acc1 = 0.f, acc2 = 0.f, acc3 = 0.f;
            #pragma unroll
            for (int k = 0; k < SS; ++k) {
                float pk = sP[k * LDP + j];
                acc0 += Freg[0][k] * pk;
                acc1 += Freg[1][k] * pk;
                acc2 += Freg[2][k] * pk;
                acc3 += Freg[3][k] * pk;
            }
            sFP[(4 * a + 0) * LDP + j] = acc0;
            sFP[(4 * a + 1) * LDP + j] = acc1;
            sFP[(4 * a + 2) * LDP + j] = acc2;
            sFP[(4 * a + 3) * LDP + j] = acc3;
        }
        // PHt[i][n] = sum_k P[i][k] H[n][k] ; row 32 gives mm[n] = H m
        if (tid < 132) {
            int i = tid >> 2, n = tid & 3;
            float s = 0.f;
            #pragma unroll
            for (int k = 0; k < SS; ++k) s += sP[i * LDP + k] * Hreg[k];
            if (i < SS) {
                sPHt[i * LDV + n] = s;
            } else {
                smm[n] = s;
                out_means[((size_t)t * BB + b) * MM + n] = s;
            }
        }
        __syncthreads(); // B1

        // ================= phase 2 =================
        if (tid < 128) {
            // FPH[i][n] = sum_k FP[i][k] * H[n][k]
            int i = tid >> 2, n = tid & 3;
            float s = 0.f;
            #pragma unroll
            for (int k = 0; k < SS; ++k) s += sFP[i * LDP + k] * Hreg[k];
            sFPH[i * LDV + n] = s;
        } else if (tid < 144) {
            // Smeas[m][n] = sum_s H[m][s] PHt[s][n] + R  (this IS the cov output)
            int q = tid - 128, m = q & 3, n = q >> 2;
            float s = 0.f;
            #pragma unroll
            for (int k = 0; k < SS; ++k) s += Hreg[k] * sPHt[k * LDV + n];
            s += sR[m * MM + n];
            sSm[m * MM + n] = s;
            out_covs[(((size_t)t * BB + b) * MM + m) * MM + n] = s;
        } else if (tid < 148) {
            sresid[tid - 144] = yv - smm[tid - 144];
        } else if (tid >= 192 && tid < 224) {
            // Fm[i] = sum_k F[i][k] m[k]
            int i = tid - 192;
            float s = 0.f;
            #pragma unroll
            for (int k = 0; k < SS; ++k) s += sF[i * LDP + k] * sm[k];
            sFm[i] = s;
        }
        if (t == TT - 1) break;   // uniform: outputs written, no update needed
        __syncthreads(); // B2

        // ================= phase 3 =================
        // FK[i][n] = sum_m FPH[i][m] * Sinv[m][n], Sinv via Cramer (redundant per thread)
        if (tid < 128) {
            int i = tid >> 2, n = tid & 3;
            int r0 = (n == 0) ? 1 : 0;
            int r1 = (n <= 1) ? 2 : 1;
            int r2 = (n <= 2) ? 3 : 2;
            float A0 = sSm[r0*4+0], A1 = sSm[r0*4+1], A2 = sSm[r0*4+2], A3 = sSm[r0*4+3];
            float B0 = sSm[r1*4+0], B1 = sSm[r1*4+1], B2 = sSm[r1*4+2], B3 = sSm[r1*4+3];
            float C0 = sSm[r2*4+0], C1 = sSm[r2*4+1], C2 = sSm[r2*4+2], C3 = sSm[r2*4+3];
            float sn = (n & 1) ? -1.f : 1.f;
            float num = 0.f, det = 0.f;
            { // m=0, cols {1,2,3}
                float mi = A1*(B2*C3 - B3*C2) - A2*(B1*C3 - B3*C1) + A3*(B1*C2 - B2*C1);
                float cof = sn * mi;
                num += sFPH[i*LDV + 0] * cof;
                det += sSm[n*4 + 0] * cof;
            }
            { // m=1, cols {0,2,3}
                float mi = A0*(B2*C3 - B3*C2) - A2*(B0*C3 - B3*C0) + A3*(B0*C2 - B2*C0);
                float cof = -sn * mi;
                num += sFPH[i*LDV + 1] * cof;
                det += sSm[n*4 + 1] * cof;
            }
            { // m=2, cols {0,1,3}
                float mi = A0*(B1*C3 - B3*C1) - A1*(B0*C3 - B3*C0) + A3*(B0*C1 - B1*C0);
                float cof = sn * mi;
                num += sFPH[i*LDV + 2] * cof;
                det += sSm[n*4 + 2] * cof;
            }
            { // m=3, cols {0,1,2}
                float mi = A0*(B1*C2 - B2*C1) - A1*(B0*C2 - B2*C0) + A2*(B0*C1 - B1*C0);
                float cof = -sn * mi;
                num += sFPH[i*LDV + 3] * cof;
                det += sSm[n*4 + 3] * cof;
            }
            sFK[i * LDV + n] = num / det;
        }
        __syncthreads(); // B3

        // ================= phase 4 =================
        // temp = FP - FK * PHt^T   (in place in sFP);  m_p = Fm + FK * resid
        {
            float ph0 = sPHt[j*LDV+0], ph1 = sPHt[j*LDV+1];
            float ph2 = sPHt[j*LDV+2], ph3 = sPHt[j*LDV+3];
            #pragma unroll
            for (int r = 0; r < 4; ++r) {
                int row = 4 * a + r;
                float v = sFP[row * LDP + j]
                        - sFK[row*LDV+0]*ph0 - sFK[row*LDV+1]*ph1
                        - sFK[row*LDV+2]*ph2 - sFK[row*LDV+3]*ph3;
                sFP[row * LDP + j] = v;
            }
        }
        if (tid < SS) {
            float mp = sFm[tid]
                     + sFK[tid*LDV+0]*sresid[0] + sFK[tid*LDV+1]*sresid[1]
                     + sFK[tid*LDV+2]*sresid[2] + sFK[tid*LDV+3]*sresid[3];
            sm[tid] = mp;
        }
        __syncthreads(); // B4

        // ================= phase 5 =================
        // P_p[i][4a+r] = sum_k temp[i][k] * F[4a+r][k] + Q[i][4a+r]
        {
            int i = j;
            float p0 = 0.f, p1 = 0.f, p2 = 0.f, p3 = 0.f;
            #pragma unroll
            for (int k = 0; k < SS; ++k) {
                float tk = sFP[i * LDP + k];
                p0 += tk * Freg[0][k];
                p1 += tk * Freg[1][k];
                p2 += tk * Freg[2][k];
                p3 += tk * Freg[3][k];
            }
            sP[i * LDP + 4*a + 0] = p0 + sQ[i * LDP + 4*a + 0];
            sP[i * LDP + 4*a + 1] = p1 + sQ[i * LDP + 4*a + 1];
            sP[i * LDP + 4*a + 2] = p2 + sQ[i * LDP + 4*a + 2];
            sP[i * LDP + 4*a + 3] = p3 + sQ[i * LDP + 4*a + 3];
        }
        __syncthreads(); // B5
    }
}

extern "C" void kernel_launch(void* const* d_in, const int* in_sizes, int n_in,
                              void* d_out, int out_size, void* d_ws, size_t ws_size,
                              hipStream_t stream) {
    const float* obs       = (const float*)d_in[0];
    const float* F         = (const float*)d_in[1];
    const float* Q         = (const float*)d_in[2];
    const float* H         = (const float*)d_in[3];
    const float* R         = (const float*)d_in[4];
    const float* init_mean = (const float*)d_in[5];
    const float* init_cov  = (const float*)d_in[6];
    float* out = (float*)d_out;

    kalman_fp32<<<BB, 256, 0, stream>>>(obs, F, Q, H, R, init_mean, init_cov, out);
}

// Round 2
// 719.863 us; speedup vs baseline: 6.0998x; 6.0998x over previous
//
#include <hip/hip_runtime.h>

#define BB 512
#define TT 256
#define SS 32
#define LDR 36   // row stride (floats): 36*4=144 B, 16B-aligned rows, odd/16 bank offset per row

__global__ __launch_bounds__(256, 2)
void kalman_v2(const float* __restrict__ obs,       // [B,T,4]
               const float* __restrict__ Fg,        // [32,32]
               const float* __restrict__ Qg,        // [32,32]
               const float* __restrict__ Hg,        // [4,32]
               const float* __restrict__ Rg,        // [4,4]
               const float* __restrict__ init_mean, // [B,32]
               const float* __restrict__ init_cov,  // [B,32,32]
               float* __restrict__ out)             // means [T,B,4] ++ covs [T,B,4,4]
{
    __shared__ __align__(16) float sP[SS * LDR];     // P (row-major, symmetric)
    __shared__ __align__(16) float sT[SS * LDR];     // FP (phase1-2), then temp^T (phase3-4)
    __shared__ __align__(16) float sH[4 * LDR];      // H rows
    __shared__ __align__(16) float sPHt[SS * 4];     // PHt[i][n], stride 4
    __shared__ __align__(16) float sPHtT[4 * LDR];   // PHt^T[n][i]
    __shared__ __align__(16) float sFPH[SS * 4];     // (F*P)*H^T rows, stride 4
    __shared__ __align__(16) float sSm[16];          // innovation covariance
    __shared__ __align__(16) float sR[16];
    __shared__ __align__(16) float sm_[SS];          // state mean
    __shared__ __align__(16) float sFm[SS];          // F*m
    __shared__ __align__(16) float sresid[4];
    __shared__ float smm[4];

    const int tid = threadIdx.x;
    const int b   = blockIdx.x;
    const int i0  = tid & 15;        // rows owned: i0, i0+16
    const int g   = tid >> 4;        // cols owned: 2g, 2g+1
    const int r1  = i0 + 16;
    const int c0  = 2 * g, c1 = 2 * g + 1;

    // ---- per-thread F rows (64 VGPRs) and Q tile (4) ----
    float F0[SS], F1[SS];
    #pragma unroll
    for (int k = 0; k < SS; ++k) {
        F0[k] = Fg[i0 * SS + k];
        F1[k] = Fg[r1 * SS + k];
    }
    const float Q0 = Qg[c0 * SS + i0];
    const float Q1 = Qg[c0 * SS + r1];
    const float Q2 = Qg[c1 * SS + i0];
    const float Q3 = Qg[c1 * SS + r1];

    // ---- stage LDS ----
    for (int e = tid; e < SS * SS; e += 256)
        sP[(e >> 5) * LDR + (e & 31)] = init_cov[(size_t)b * SS * SS + e];
    if (tid < SS)  sm_[tid] = init_mean[b * SS + tid];
    if (tid < 128) sH[(tid >> 5) * LDR + (tid & 31)] = Hg[tid];
    if (tid < 16)  sR[tid] = Rg[tid];
    __syncthreads();  // B0

    float* out_means = out;
    float* out_covs  = out + (size_t)TT * BB * 4;

    for (int t = 0; t < TT; ++t) {
        // ============ phase 1: FP = F*P (all threads), PHt / mm / y-prefetch ============
        float yv = 0.f;
        if (tid >= 144 && tid < 148)
            yv = obs[((size_t)b * TT + t) * 4 + (tid - 144)];

        float fp00 = 0.f, fp01 = 0.f, fp10 = 0.f, fp11 = 0.f;
        #pragma unroll
        for (int k = 0; k < SS; ++k) {
            float2 p = *(const float2*)&sP[k * LDR + c0];
            fp00 = fmaf(F0[k], p.x, fp00);
            fp01 = fmaf(F0[k], p.y, fp01);
            fp10 = fmaf(F1[k], p.x, fp10);
            fp11 = fmaf(F1[k], p.y, fp11);
        }
        *(float2*)&sT[i0 * LDR + c0] = make_float2(fp00, fp01);
        *(float2*)&sT[r1 * LDR + c0] = make_float2(fp10, fp11);

        if (tid < 128) {
            // PHt[i][n] = sum_k P[i][k] H[n][k]
            const int i = tid >> 2, n = tid & 3;
            float s = 0.f;
            #pragma unroll
            for (int q = 0; q < 8; ++q) {
                float4 pv = *(const float4*)&sP[i * LDR + 4 * q];
                float4 hv = *(const float4*)&sH[n * LDR + 4 * q];
                s += pv.x * hv.x + pv.y * hv.y + pv.z * hv.z + pv.w * hv.w;
            }
            sPHt[i * 4 + n]    = s;
            sPHtT[n * LDR + i] = s;
        } else if (tid < 132) {
            // mm[n] = H[n,:] . m   (this step's mean output)
            const int n = tid - 128;
            float s = 0.f;
            #pragma unroll
            for (int q = 0; q < 8; ++q) {
                float4 hv = *(const float4*)&sH[n * LDR + 4 * q];
                float4 mv = *(const float4*)&sm_[4 * q];
                s += hv.x * mv.x + hv.y * mv.y + hv.z * mv.z + hv.w * mv.w;
            }
            smm[n] = s;
            out_means[((size_t)t * BB + b) * 4 + n] = s;
        }
        __syncthreads();  // B1

        // ============ phase 2: FPH, Smeas(+output), resid, Fm ============
        if (tid < 128) {
            const int i = tid >> 2, n = tid & 3;
            float s = 0.f;
            #pragma unroll
            for (int q = 0; q < 8; ++q) {
                float4 fv = *(const float4*)&sT[i * LDR + 4 * q];
                float4 hv = *(const float4*)&sH[n * LDR + 4 * q];
                s += fv.x * hv.x + fv.y * hv.y + fv.z * hv.z + fv.w * hv.w;
            }
            sFPH[i * 4 + n] = s;
        } else if (tid < 144) {
            // Smeas[m][n] = H[m,:] . PHt[:,n] + R  == this step's cov output
            const int q2 = tid - 128, m = q2 & 3, n = q2 >> 2;
            float s = 0.f;
            #pragma unroll
            for (int q = 0; q < 8; ++q) {
                float4 hv = *(const float4*)&sH[m * LDR + 4 * q];
                float4 pv = *(const float4*)&sPHtT[n * LDR + 4 * q];
                s += hv.x * pv.x + hv.y * pv.y + hv.z * pv.z + hv.w * pv.w;
            }
            s += sR[m * 4 + n];
            sSm[m * 4 + n] = s;
            out_covs[(((size_t)t * BB + b) * 4 + m) * 4 + n] = s;
        } else if (tid < 148) {
            sresid[tid - 144] = yv - smm[tid - 144];
        } else if (tid >= 240) {
            // Fm rows i0, r1 (uses register F rows)
            float s0 = 0.f, s1 = 0.f;
            #pragma unroll
            for (int k = 0; k < SS; ++k) {
                float mv = sm_[k];
                s0 = fmaf(F0[k], mv, s0);
                s1 = fmaf(F1[k], mv, s1);
            }
            sFm[i0] = s0;
            sFm[r1] = s1;
        }
        if (t == TT - 1) break;  // outputs for final step written; no update needed
        __syncthreads();  // B2

        // ============ phase 3: redundant 4x4 inverse, FK rows, temp^T, mean update ======
        {
            float4 Ma = *(const float4*)&sSm[0];
            float4 Mb = *(const float4*)&sSm[4];
            float4 Mc = *(const float4*)&sSm[8];
            float4 Md = *(const float4*)&sSm[12];
            const float M0 = Ma.x, M1 = Ma.y, M2 = Ma.z, M3 = Ma.w;
            const float M4 = Mb.x, M5 = Mb.y, M6 = Mb.z, M7 = Mb.w;
            const float M8 = Mc.x, M9 = Mc.y, M10 = Mc.z, M11 = Mc.w;
            const float M12 = Md.x, M13 = Md.y, M14 = Md.z, M15 = Md.w;

            const float A2323 = M10*M15 - M11*M14;
            const float A1323 = M9 *M15 - M11*M13;
            const float A1223 = M9 *M14 - M10*M13;
            const float A0323 = M8 *M15 - M11*M12;
            const float A0223 = M8 *M14 - M10*M12;
            const float A0123 = M8 *M13 - M9 *M12;
            const float A2313 = M6 *M15 - M7 *M14;
            const float A1313 = M5 *M15 - M7 *M13;
            const float A1213 = M5 *M14 - M6 *M13;
            const float A2312 = M6 *M11 - M7 *M10;
            const float A1312 = M5 *M11 - M7 *M9;
            const float A1212 = M5 *M10 - M6 *M9;
            const float A0313 = M4 *M15 - M7 *M12;
            const float A0213 = M4 *M14 - M6 *M12;
            const float A0312 = M4 *M11 - M7 *M8;
            const float A0212 = M4 *M10 - M6 *M8;
            const float A0113 = M4 *M13 - M5 *M12;
            const float A0112 = M4 *M9  - M5 *M8;

            const float det = M0*(M5*A2323 - M6*A1323 + M7*A1223)
                            - M1*(M4*A2323 - M6*A0323 + M7*A0223)
                            + M2*(M4*A1323 - M5*A0323 + M7*A0123)
                            - M3*(M4*A1223 - M5*A0223 + M6*A0123);
            const float invdet = 1.0f / det;

            float4 fa = *(const float4*)&sFPH[i0 * 4];
            float4 fb = *(const float4*)&sFPH[r1 * 4];
            fa.x *= invdet; fa.y *= invdet; fa.z *= invdet; fa.w *= invdet;
            fb.x *= invdet; fb.y *= invdet; fb.z *= invdet; fb.w *= invdet;

            // adjugate (inv*det), consumed immediately into FK rows
            float fk00, fk01, fk02, fk03, fk10, fk11, fk12, fk13;
            {
                const float i00 =  (M5*A2323 - M6*A1323 + M7*A1223);
                const float i10 = -(M4*A2323 - M6*A0323 + M7*A0223);
                const float i20 =  (M4*A1323 - M5*A0323 + M7*A0123);
                const float i30 = -(M4*A1223 - M5*A0223 + M6*A0123);
                fk00 = fa.x*i00 + fa.y*i10 + fa.z*i20 + fa.w*i30;
                fk10 = fb.x*i00 + fb.y*i10 + fb.z*i20 + fb.w*i30;
            }
            {
                const float i01 = -(M1*A2323 - M2*A1323 + M3*A1223);
                const float i11 =  (M0*A2323 - M2*A0323 + M3*A0223);
                const float i21 = -(M0*A1323 - M1*A0323 + M3*A0123);
                const float i31 =  (M0*A1223 - M1*A0223 + M2*A0123);
                fk01 = fa.x*i01 + fa.y*i11 + fa.z*i21 + fa.w*i31;
                fk11 = fb.x*i01 + fb.y*i11 + fb.z*i21 + fb.w*i31;
            }
            {
                const float i02 =  (M1*A2313 - M2*A1313 + M3*A1213);
                const float i12 = -(M0*A2313 - M2*A0313 + M3*A0213);
                const float i22 =  (M0*A1313 - M1*A0313 + M3*A0113);
                const float i32 = -(M0*A1213 - M1*A0213 + M2*A0113);
                fk02 = fa.x*i02 + fa.y*i12 + fa.z*i22 + fa.w*i32;
                fk12 = fb.x*i02 + fb.y*i12 + fb.z*i22 + fb.w*i32;
            }
            {
                const float i03 = -(M1*A2312 - M2*A1312 + M3*A1212);
                const float i13 =  (M0*A2312 - M2*A0312 + M3*A0212);
                const float i23 = -(M0*A1312 - M1*A0312 + M3*A0112);
                const float i33 =  (M0*A1212 - M1*A0212 + M2*A0112);
                fk03 = fa.x*i03 + fa.y*i13 + fa.z*i23 + fa.w*i33;
                fk13 = fb.x*i03 + fb.y*i13 + fb.z*i23 + fb.w*i33;
            }

            // temp = FP - FK * PHt^T  (2x2 tile in regs), store transposed into sT
            float4 pa = *(const float4*)&sPHt[c0 * 4];
            float4 pb = *(const float4*)&sPHt[c1 * 4];
            float t00 = fp00 - (fk00*pa.x + fk01*pa.y + fk02*pa.z + fk03*pa.w);
            float t01 = fp01 - (fk00*pb.x + fk01*pb.y + fk02*pb.z + fk03*pb.w);
            float t10 = fp10 - (fk10*pa.x + fk11*pa.y + fk12*pa.z + fk13*pa.w);
            float t11 = fp11 - (fk10*pb.x + fk11*pb.y + fk12*pb.z + fk13*pb.w);
            sT[c0 * LDR + i0] = t00;   // sT[c][r] = temp[r][c]
            sT[c1 * LDR + i0] = t01;
            sT[c0 * LDR + r1] = t10;
            sT[c1 * LDR + r1] = t11;

            if (g == 0) {  // mean update+predict: m_p = F*m + FK*resid
                float4 rs = *(const float4*)&sresid[0];
                sm_[i0] = sFm[i0] + fk00*rs.x + fk01*rs.y + fk02*rs.z + fk03*rs.w;
                sm_[r1] = sFm[r1] + fk10*rs.x + fk11*rs.y + fk12*rs.z + fk13*rs.w;
            }
        }
        __syncthreads();  // B3

        // ============ phase 4: P_p = temp * F^T + Q  (reads temp^T contiguously) ========
        {
            float p00 = 0.f, p01 = 0.f, p10 = 0.f, p11 = 0.f;
            #pragma unroll
            for (int k = 0; k < SS; ++k) {
                float2 tv = *(const float2*)&sT[k * LDR + c0];  // temp[c0][k], temp[c1][k]
                p00 = fmaf(tv.x, F0[k], p00);   // P_p[c0][i0]
                p01 = fmaf(tv.x, F1[k], p01);   // P_p[c0][r1]
                p10 = fmaf(tv.y, F0[k], p10);   // P_p[c1][i0]
                p11 = fmaf(tv.y, F1[k], p11);   // P_p[c1][r1]
            }
            sP[c0 * LDR + i0] = p00 + Q0;
            sP[c0 * LDR + r1] = p01 + Q1;
            sP[c1 * LDR + i0] = p10 + Q2;
            sP[c1 * LDR + r1] = p11 + Q3;
        }
        __syncthreads();  // B4
    }
}

extern "C" void kernel_launch(void* const* d_in, const int* in_sizes, int n_in,
                              void* d_out, int out_size, void* d_ws, size_t ws_size,
                              hipStream_t stream) {
    const float* obs       = (const float*)d_in[0];
    const float* F         = (const float*)d_in[1];
    const float* Q         = (const float*)d_in[2];
    const float* H         = (const float*)d_in[3];
    const float* R         = (const float*)d_in[4];
    const float* init_mean = (const float*)d_in[5];
    const float* init_cov  = (const float*)d_in[6];
    float* out = (float*)d_out;

    kalman_v2<<<BB, 256, 0, stream>>>(obs, F, Q, H, R, init_mean, init_cov, out);
}